// Round 18
// baseline (2025.576 us; speedup 1.0000x reference)
//
#include <hip/hip_runtime.h>
#include <hip/hip_bf16.h>
#include <cstdint>
#include <cstddef>

// Problem constants: L=256, B=16, I=2048, H=2048, S=R=T=32
#define L_DIM 256
#define B_DIM 16
#define I_DIM 2048
#define H_DIM 2048
#define G4    8192
#define MROWS 4096
#define NWGL  128            // LSTM workgroups (each owns 16 hidden units)
#define NPRJ  16             // projection workgroups
#define NSCN  16             // scan workgroups (one per batch)

// Sentinels (NaN encodings — unreachable by the finite bounded arithmetic
// of every value exchanged through these buffers)
#define SENT_F16  0x7C01u
#define SENT_BF16 0x7FC1u
#define SENT_F32  0x7FC00000u

typedef __hip_bfloat16 bf16;
typedef __bf16 bf16x8_t __attribute__((ext_vector_type(8)));
typedef _Float16 f16x8_t __attribute__((ext_vector_type(8)));
typedef _Float16 f16x4_t __attribute__((ext_vector_type(4)));
typedef float f32x4_t   __attribute__((ext_vector_type(4)));
typedef unsigned int u32x4 __attribute__((ext_vector_type(4)));

__device__ __forceinline__ bf16 f2b(float f) { return __float2bfloat16(f); }

__device__ __forceinline__ void gl_lds16(const void* g, void* l) {
  __builtin_amdgcn_global_load_lds(
      (const __attribute__((address_space(1))) unsigned int*)g,
      (__attribute__((address_space(3))) unsigned int*)l, 16, 0, 0);
}

__device__ __forceinline__ float sigmoidf_(float x) { return 1.f / (1.f + expf(-x)); }

// Coherent (IC-through) access helpers — proven fence-free protocol (r8).
__device__ __forceinline__ f16x8_t load_f16x8_sc(const _Float16* p) {
  f16x8_t r;
  asm volatile("global_load_dwordx4 %0, %1, off sc0 sc1" : "=v"(r) : "v"(p));
  return r;
}
__device__ __forceinline__ bf16x8_t load_bf16x8_sc(const bf16* p) {
  bf16x8_t r;
  asm volatile("global_load_dwordx4 %0, %1, off sc0 sc1" : "=v"(r) : "v"(p));
  return r;
}
__device__ __forceinline__ float load_f32_sc(const float* p) {
  float r;
  asm volatile("global_load_dword %0, %1, off sc0 sc1" : "=v"(r) : "v"(p));
  return r;
}
__device__ __forceinline__ void store_short_sc(void* p, unsigned int v) {
  asm volatile("global_store_short %0, %1, off sc0 sc1" :: "v"(p), "v"(v) : "memory");
}
__device__ __forceinline__ void store_f32_sc(void* p, float v) {
  asm volatile("global_store_dword %0, %1, off sc0 sc1" :: "v"(p), "v"(v) : "memory");
}

__device__ __forceinline__ unsigned sent16x8(f16x8_t v, unsigned pat) {
  const u32x4 u = __builtin_bit_cast(u32x4, v);
  unsigned b = 0;
#pragma unroll
  for (int i = 0; i < 4; ++i) {
    b |= ((u[i] & 0xFFFFu) == pat);
    b |= ((u[i] >> 16) == pat);
  }
  return b;
}
__device__ __forceinline__ unsigned sentb16x8(bf16x8_t v, unsigned pat) {
  const u32x4 u = __builtin_bit_cast(u32x4, v);
  unsigned b = 0;
#pragma unroll
  for (int i = 0; i < 4; ++i) {
    b |= ((u[i] & 0xFFFFu) == pat);
    b |= ((u[i] >> 16) == pat);
  }
  return b;
}

// ---------------------------------------------------------------------------
// K0: prep — fp16 casts, bf16 hi/lo FWM weights, h0 fp16, sentinel prefill
// ---------------------------------------------------------------------------
__global__ void prep_kernel(const float* __restrict__ Wih, const float* __restrict__ Whh,
                            const float* __restrict__ inp, const float* __restrict__ Www,
                            const float* __restrict__ Wwb, const float* __restrict__ Wrw,
                            const float* __restrict__ h0,
                            _Float16* __restrict__ Wih_f, _Float16* __restrict__ Whh_f,
                            _Float16* __restrict__ inp_f,
                            bf16* __restrict__ Wq_hi, bf16* __restrict__ Wq_lo,
                            bf16* __restrict__ Wr_hi, bf16* __restrict__ Wr_lo,
                            float* __restrict__ wbpad,
                            _Float16* __restrict__ Xh,
                            bf16* __restrict__ XhHi, bf16* __restrict__ XhLo,
                            float* __restrict__ Wall, float* __restrict__ RVall)
{
  size_t idx0 = (size_t)blockIdx.x * blockDim.x + threadIdx.x;
  size_t stride = (size_t)gridDim.x * blockDim.x;
  for (size_t i = idx0; i < 16777216ull; i += stride) {
    Wih_f[i] = (_Float16)Wih[i];
    Whh_f[i] = (_Float16)Whh[i];
  }
  for (size_t i = idx0; i < 8388608ull; i += stride) {
    inp_f[i] = (_Float16)inp[i];
    // sentinel prefill: Xh slots 1..256, XhHi/XhLo all rows
    ((unsigned short*)Xh)[32768 + i]   = (unsigned short)SENT_F16;
    ((unsigned short*)XhHi)[i]         = (unsigned short)SENT_BF16;
    ((unsigned short*)XhLo)[i]         = (unsigned short)SENT_BF16;
  }
  for (size_t i = idx0; i < 524288ull; i += stride) {
    ((unsigned int*)Wall)[i]  = SENT_F32;
    ((unsigned int*)RVall)[i] = SENT_F32;
  }
  for (size_t i = idx0; i < 262144ull; i += stride) {
    size_t r = i >> 11;
    float q = (r < 97) ? Www[i] : 0.f;
    bf16 qh = f2b(q);
    Wq_hi[i] = qh;
    Wq_lo[i] = f2b(q - (float)qh);
    float rr = Wrw[i];
    bf16 rh = f2b(rr);
    Wr_hi[i] = rh;
    Wr_lo[i] = f2b(rr - (float)rh);
  }
  for (size_t i = idx0; i < 128ull; i += stride) wbpad[i] = (i < 97) ? Wwb[i] : 0.f;
  for (size_t i = idx0; i < 32768ull; i += stride) Xh[i] = (_Float16)h0[i];  // slot 0
}

// ---------------------------------------------------------------------------
// K1: fp16 NT GEMM  C = A * B^T + bias -> fp16 Gin2[t][wg][gate][jj][bb].
// Coalesced f16x4 epilogue (round 16, proven).
// ---------------------------------------------------------------------------
__global__ __launch_bounds__(256) void gemm_f16(const _Float16* __restrict__ A,
                                                const _Float16* __restrict__ B,
                                                const float* __restrict__ bih,
                                                const float* __restrict__ bhh,
                                                _Float16* __restrict__ Gin2,
                                                int M, int N, int K)
{
  __shared__ __align__(16) _Float16 As[128 * 32];
  __shared__ __align__(16) _Float16 Bs[128 * 32];
  const int tid  = threadIdx.x;
  const int lane = tid & 63;
  const int w    = tid >> 6;
  const int wm   = w >> 1, wn = w & 1;
  const int m0   = blockIdx.x * 128, n0 = blockIdx.y * 128;

  f32x4_t acc[4][4];
#pragma unroll
  for (int m = 0; m < 4; ++m)
#pragma unroll
    for (int n = 0; n < 4; ++n) acc[m][n] = (f32x4_t){0.f, 0.f, 0.f, 0.f};

  for (int k0 = 0; k0 < K; k0 += 32) {
#pragma unroll
    for (int r = 0; r < 2; ++r) {
      const int base = w * 2048 + r * 1024;
      const int off  = base + lane * 16;
      const int e    = off >> 1;
      const int row  = e >> 5;
      const int col  = e & 31;
      gl_lds16(A + (size_t)(m0 + row) * K + (k0 + col), (char*)As + base);
      gl_lds16(B + (size_t)(n0 + row) * K + (k0 + col), (char*)Bs + base);
    }
    __syncthreads();

    f16x8_t af[4], bfr[4];
    const int kb = (lane >> 4) * 16;
#pragma unroll
    for (int m = 0; m < 4; ++m)
      af[m] = *reinterpret_cast<const f16x8_t*>((const char*)As + (wm * 64 + m * 16 + (lane & 15)) * 64 + kb);
#pragma unroll
    for (int n = 0; n < 4; ++n)
      bfr[n] = *reinterpret_cast<const f16x8_t*>((const char*)Bs + (wn * 64 + n * 16 + (lane & 15)) * 64 + kb);
#pragma unroll
    for (int m = 0; m < 4; ++m)
#pragma unroll
      for (int n = 0; n < 4; ++n)
        acc[m][n] = __builtin_amdgcn_mfma_f32_16x16x32_f16(af[m], bfr[n], acc[m][n], 0, 0, 0);
    __syncthreads();
  }

  const int jj = lane & 15;
#pragma unroll
  for (int n = 0; n < 4; ++n) {
    const int colb = n0 + wn * 64 + n * 16;
    const int gate = colb >> 11;
    const int wg   = (colb & 2047) >> 4;
    const float bv = bih[colb + jj] + bhh[colb + jj];
#pragma unroll
    for (int m = 0; m < 4; ++m) {
      const int rowb = m0 + wm * 64 + m * 16;
      const int t = rowb >> 4;
      f16x4_t v4;
#pragma unroll
      for (int r = 0; r < 4; ++r) v4[r] = (_Float16)(acc[m][n][r] + bv);
      *reinterpret_cast<f16x4_t*>(
          Gin2 + (((size_t)t * NWGL + wg) * 4 + gate) * 256 + jj * 16 + (lane >> 4) * 4) = v4;
    }
  }
}

// ---------------------------------------------------------------------------
// K2: FUSED persistent RNN (160 WGs x 512 thr, cooperative).
// Flag-free sentinel dataflow; ROUND 18 fix: sched_barrier(0) INSIDE every
// poll loop, immediately after vmcnt(0), BEFORE the sentinel test (rule #18:
// hipcc otherwise hoists the register-only test above the waitcnt).
// ---------------------------------------------------------------------------
__global__ __launch_bounds__(512, 2) void fused_rnn(
    const _Float16* __restrict__ Whh,
    const _Float16* __restrict__ Gin2,   // (256,128,4,16,16) fp16
    const float* __restrict__ bih, const float* __restrict__ bhh,
    const float* __restrict__ c0,
    const bf16* __restrict__ Wq_hi, const bf16* __restrict__ Wq_lo,
    const bf16* __restrict__ Wr_hi, const bf16* __restrict__ Wr_lo,
    const float* __restrict__ wbpad, const float* __restrict__ Wrb,
    const float* __restrict__ F0,
    _Float16* __restrict__ Xh,
    bf16* __restrict__ XhHi, bf16* __restrict__ XhLo,
    float* __restrict__ Wall, float* __restrict__ RVall,
    _Float16* __restrict__ Gbuf)
{
  __shared__ float part[8][4][16][17];          // lstm reduce; proj uses [][0]
  __shared__ float s_s[32], s_r[32], s_tv[32], s_bb;
  __shared__ float s_rv[128];
  __shared__ float s_v[32];
  __shared__ float s_red[8];

  const int wgid = blockIdx.x;
  const int tid  = threadIdx.x;
  const int lane = tid & 63;
  const int wv   = tid >> 6;          // 0..7

  if (wgid < NWGL) {
    // ===================== LSTM =====================
    const int wg = wgid;
    const int j0 = wg * 16;
    const int kw = wv * 256;

    f16x8_t whh[4][8];
    {
      const int nn  = lane & 15;
      const int kfo = (lane >> 4) * 8;
#pragma unroll
      for (int g = 0; g < 4; ++g) {
        const size_t grow = (size_t)(g * H_DIM + j0 + nn) * 2048;
#pragma unroll
        for (int ks = 0; ks < 8; ++ks)
          whh[g][ks] = *reinterpret_cast<const f16x8_t*>(Whh + grow + kw + ks * 32 + kfo);
      }
    }

    float c_reg = 0.f, cbr0 = 0.f, cbr1 = 0.f, cbr2 = 0.f, cbr3 = 0.f;
    if (tid < 256) {
      const int bb = tid & 15, jj = tid >> 4;
      const int j = j0 + jj;
      c_reg = c0[bb * H_DIM + j];
      cbr0 = bih[0 * H_DIM + j] + bhh[0 * H_DIM + j];
      cbr1 = bih[1 * H_DIM + j] + bhh[1 * H_DIM + j];
      cbr2 = bih[2 * H_DIM + j] + bhh[2 * H_DIM + j];
      cbr3 = bih[3 * H_DIM + j] + bhh[3 * H_DIM + j];
    }

    const size_t arow = (size_t)(lane & 15) * 2048 + kw + (lane >> 4) * 8;

    for (int t = 0; t < L_DIM; ++t) {
      float gin0 = 0.f, gin1 = 0.f, gin2v = 0.f, gin3 = 0.f;
      if (tid < 256) {
        const _Float16* gbase = Gin2 + ((size_t)t * NWGL + wg) * 1024;
        gin0  = (float)gbase[0 * 256 + tid];
        gin1  = (float)gbase[1 * 256 + tid];
        gin2v = (float)gbase[2 * 256 + tid];
        gin3  = (float)gbase[3 * 256 + tid];
      }

      // sentinel-poll + load h slice (slot t): detect==load, one round trip
      const size_t hoff = (size_t)t * 32768 + arow;
      f16x8_t hf[8];
      while (true) {
#pragma unroll
        for (int ks = 0; ks < 8; ++ks)
          hf[ks] = load_f16x8_sc(Xh + hoff + ks * 32);
        asm volatile("s_waitcnt vmcnt(0)" ::: "memory");
        __builtin_amdgcn_sched_barrier(0);   // rule #18: test AFTER the wait
        unsigned bad = 0;
#pragma unroll
        for (int ks = 0; ks < 8; ++ks) bad |= sent16x8(hf[ks], SENT_F16);
        if (!__any(bad)) break;
        __builtin_amdgcn_s_sleep(1);
      }
      __builtin_amdgcn_sched_barrier(0);

      f32x4_t acc[4];
#pragma unroll
      for (int g = 0; g < 4; ++g) acc[g] = (f32x4_t){0.f, 0.f, 0.f, 0.f};
#pragma unroll
      for (int ks = 0; ks < 8; ++ks) {
#pragma unroll
        for (int g = 0; g < 4; ++g)
          acc[g] = __builtin_amdgcn_mfma_f32_16x16x32_f16(hf[ks], whh[g][ks], acc[g], 0, 0, 0);
      }
#pragma unroll
      for (int g = 0; g < 4; ++g)
#pragma unroll
        for (int r = 0; r < 4; ++r)
          part[wv][g][(lane >> 4) * 4 + r][lane & 15] = acc[g][r];
      __syncthreads();

      if (tid < 256) {
        const int bb = tid & 15, jj = tid >> 4;
        float g4[4] = {gin0, gin1, gin2v, gin3};
        const float cb4[4] = {cbr0, cbr1, cbr2, cbr3};
#pragma unroll
        for (int g = 0; g < 4; ++g) {
          float s = 0.f;
#pragma unroll
          for (int v = 0; v < 8; ++v) s += part[v][g][bb][jj];
          g4[g] += s + cb4[g];
        }
        const float i_ = sigmoidf_(g4[0]);
        const float f_ = sigmoidf_(g4[1]);
        const float g_ = tanhf(g4[2]);
        const float o_ = sigmoidf_(g4[3]);
        c_reg = f_ * c_reg + i_ * g_;
        const float h = o_ * tanhf(c_reg);
        const int bj = bb * 2048 + j0 + jj;
        const _Float16 hF = (_Float16)h;
        const bf16 hhv = f2b(h);
        const bf16 hlv = f2b(h - (float)hhv);
        const size_t xi = ((size_t)t * 16 + bb) * 2048 + j0 + jj;
        // fire-and-forget write-through stores: no drain, no flag
        store_short_sc(Xh + (size_t)(t + 1) * 32768 + bj,
                       (unsigned int)__builtin_bit_cast(unsigned short, hF));
        store_short_sc(XhHi + xi,
                       (unsigned int)__builtin_bit_cast(unsigned short, hhv));
        store_short_sc(XhLo + xi,
                       (unsigned int)__builtin_bit_cast(unsigned short, hlv));
      }
      __syncthreads();                 // part[] reuse fence only
    }

  } else if (wgid < NWGL + NPRJ) {
    // ===================== PROJECTION =====================
    const int p   = wgid - NWGL;
    const int kw  = wv * 256;
    const int nn  = lane & 15;
    const int kfo = (lane >> 4) * 8;

    bf16x8_t wbh[8], wbl[8];
    {
      const bf16* Bh = (p < 8) ? Wq_hi : Wr_hi;
      const bf16* Bl = (p < 8) ? Wq_lo : Wr_lo;
      const int brow = (p < 8) ? (p * 16 + nn) : ((p - 8) * 16 + nn);
#pragma unroll
      for (int ks = 0; ks < 8; ++ks) {
        const size_t o = (size_t)brow * 2048 + kw + ks * 32 + kfo;
        wbh[ks] = *reinterpret_cast<const bf16x8_t*>(Bh + o);
        wbl[ks] = *reinterpret_cast<const bf16x8_t*>(Bl + o);
      }
    }
    float biasv = 0.f;
    if (tid < 256) {
      const int oo = tid >> 4;
      biasv = (p < 8) ? wbpad[p * 16 + oo] : Wrb[(p - 8) * 16 + oo];
    }

    const size_t axrow = (size_t)(lane & 15) * 2048 + kw + kfo;

    for (int t = 0; t < L_DIM; ++t) {
      const size_t xoff = (size_t)t * 32768 + axrow;
      bf16x8_t xh[8], xl[8];
      while (true) {
#pragma unroll
        for (int ks = 0; ks < 8; ++ks) {
          xh[ks] = load_bf16x8_sc(XhHi + xoff + ks * 32);
          xl[ks] = load_bf16x8_sc(XhLo + xoff + ks * 32);
        }
        asm volatile("s_waitcnt vmcnt(0)" ::: "memory");
        __builtin_amdgcn_sched_barrier(0);   // rule #18
        unsigned bad = 0;
#pragma unroll
        for (int ks = 0; ks < 8; ++ks) {
          bad |= sentb16x8(xh[ks], SENT_BF16);
          bad |= sentb16x8(xl[ks], SENT_BF16);
        }
        if (!__any(bad)) break;
        __builtin_amdgcn_s_sleep(1);
      }
      __builtin_amdgcn_sched_barrier(0);

      f32x4_t acc = {0.f, 0.f, 0.f, 0.f};
#pragma unroll
      for (int ks = 0; ks < 8; ++ks) {
        acc = __builtin_amdgcn_mfma_f32_16x16x32_bf16(xh[ks], wbh[ks], acc, 0, 0, 0);
        acc = __builtin_amdgcn_mfma_f32_16x16x32_bf16(xh[ks], wbl[ks], acc, 0, 0, 0);
        acc = __builtin_amdgcn_mfma_f32_16x16x32_bf16(xl[ks], wbh[ks], acc, 0, 0, 0);
      }
#pragma unroll
      for (int r = 0; r < 4; ++r)
        part[wv][0][(lane >> 4) * 4 + r][lane & 15] = acc[r];
      __syncthreads();

      if (tid < 256) {
        const int bb = tid & 15, oo = tid >> 4;
        float s = 0.f;
#pragma unroll
        for (int v = 0; v < 8; ++v) s += part[v][0][bb][oo];
        s += biasv;
        float* dst;
        if (p < 8) {
          dst = Wall + (size_t)(t * 16 + bb) * 128 + p * 16 + oo;
        } else {
          s = tanhf(s);
          dst = RVall + (size_t)(t * 16 + bb) * 128 + (p - 8) * 16 + oo;
        }
        store_f32_sc(dst, s);          // fire-and-forget
      }
      __syncthreads();                 // part[] reuse fence only
    }

  } else {
    // ===================== FWM F-SCAN =====================
    const int b     = wgid - NWGL - NPRJ;
    const int si    = lane >> 1;
    const int rbase = 16 * (lane & 1);
    const int tl    = lane & 31;

    float F[16][4];
#pragma unroll
    for (int i = 0; i < 16; ++i)
#pragma unroll
      for (int j = 0; j < 4; ++j)
        F[i][j] = F0[((size_t)b * 1024 + (16 * lane + i)) * 32 + 4 * wv + j];

    float N = 0.f;
    {
      float loc = 0.f;
#pragma unroll
      for (int i = 0; i < 16; ++i)
#pragma unroll
        for (int j = 0; j < 4; ++j) loc += F[i][j] * F[i][j];
#pragma unroll
      for (int m = 1; m < 64; m <<= 1) loc += __shfl_xor(loc, m);
      if (lane == 0) s_red[wv] = loc;
      __syncthreads();
#pragma unroll
      for (int k = 0; k < 8; ++k) N += s_red[k];
    }

    for (int t = 0; t < 256; ++t) {
      float wpre = 0.f, rvpre = 0.f;
      if (tid < 97) {
        do {
          wpre = load_f32_sc(Wall + (size_t)(t * 16 + b) * 128 + tid);
          asm volatile("s_waitcnt vmcnt(0)" ::: "memory");
          __builtin_amdgcn_sched_barrier(0);   // rule #18
        } while (__builtin_bit_cast(unsigned int, wpre) == SENT_F32);
      }
      if (tid >= 128 && tid < 256) {
        do {
          rvpre = load_f32_sc(RVall + (size_t)(t * 16 + b) * 128 + tid - 128);
          asm volatile("s_waitcnt vmcnt(0)" ::: "memory");
          __builtin_amdgcn_sched_barrier(0);   // rule #18
        } while (__builtin_bit_cast(unsigned int, rvpre) == SENT_F32);
      }
      __syncthreads();                // A: prior step's s_* readers done
      if (tid < 32)       s_s[tid]       = tanhf(wpre);
      else if (tid < 64)  s_r[tid - 32]  = tanhf(wpre);
      else if (tid < 96)  s_tv[tid - 64] = tanhf(wpre);
      else if (tid == 96) s_bb           = sigmoidf_(wpre + 1.f);
      else if (tid >= 128 && tid < 256) s_rv[tid - 128] = rvpre;
      __syncthreads();                // B

      const float sv = s_s[si];
      float sr[16];
#pragma unroll
      for (int i = 0; i < 16; ++i) sr[i] = sv * s_r[rbase + i];

      float vv4[4];
#pragma unroll
      for (int j = 0; j < 4; ++j) {
        float pp = 0.f;
#pragma unroll
        for (int i = 0; i < 16; ++i) pp += sr[i] * F[i][j];
#pragma unroll
        for (int m = 1; m < 64; m <<= 1) pp += __shfl_xor(pp, m);
        vv4[j] = pp;
      }
      if (lane == 0) {
#pragma unroll
        for (int j = 0; j < 4; ++j) s_v[4 * wv + j] = vv4[j];
      }
      __syncthreads();                // C

      const float vt  = s_v[tl];
      const float ut  = s_bb * (s_tv[tl] - vt);
      const float sl  = s_s[tl];
      const float rl  = s_r[tl];
      float uv = ut * vt, uu = ut * ut, ss = sl * sl, rr = rl * rl;
#pragma unroll
      for (int m = 1; m < 32; m <<= 1) {
        uv += __shfl_xor(uv, m);
        uu += __shfl_xor(uu, m);
        ss += __shfl_xor(ss, m);
        rr += __shfl_xor(rr, m);
      }
      const float Np  = N + 2.f * uv + ss * rr * uu;
      const float n_  = sqrtf(Np);
      const float inv = 1.f / (fmaxf(n_ - 1.f, 0.f) + 1.f);
      N = Np * inv * inv;

      float uw[4];
#pragma unroll
      for (int j = 0; j < 4; ++j) uw[j] = __shfl(ut, 4 * wv + j);
#pragma unroll
      for (int i = 0; i < 16; ++i)
#pragma unroll
        for (int j = 0; j < 4; ++j)
          F[i][j] = (F[i][j] + sr[i] * uw[j]) * inv;

      _Float16* gout = Gbuf + ((size_t)(t * 16 + b) * 3) * 1024;
#pragma unroll
      for (int jit = 0; jit < 3; ++jit) {
        float rjv[16];
#pragma unroll
        for (int i = 0; i < 16; ++i) rjv[i] = s_rv[32 + 32 * jit + rbase + i];
        f16x4_t gv;
#pragma unroll
        for (int j = 0; j < 4; ++j) {
          float g = 0.f;
#pragma unroll
          for (int i = 0; i < 16; ++i) g += rjv[i] * F[i][j];
          g += __shfl_xor(g, 1);
          gv[j] = (_Float16)g;
        }
        if ((lane & 1) == 0)
          *reinterpret_cast<f16x4_t*>(gout + jit * 1024 + (lane >> 1) * 32 + 4 * wv) = gv;
      }
    }
  }
}

// ---------------------------------------------------------------------------
// K3: fused q-readout + output. One block per row (t*16+b).
// ---------------------------------------------------------------------------
__global__ __launch_bounds__(256) void qread_out(const _Float16* __restrict__ Gbuf,  // (4096,3,32,32) f16
                                                 const float* __restrict__ RVall,    // (4096,128)
                                                 const bf16* __restrict__ Xh1Hi,
                                                 const bf16* __restrict__ Xh1Lo,
                                                 const float* __restrict__ Wlin,     // (2048,32)
                                                 const float* __restrict__ blin,
                                                 float* __restrict__ out)
{
  __shared__ float qs[32];
  const int row = blockIdx.x;          // t*16+b
  const int tid = threadIdx.x;

  if (tid < 64) {
    const int lane  = tid;
    const int tq    = lane & 31;
    const int ihalf = (lane >> 5) * 16;
    const _Float16* G = Gbuf + (size_t)row * 3 * 1024;
    float q = RVall[(size_t)row * 128 + tq];
#pragma unroll 1
    for (int jit = 0; jit < 3; ++jit) {
      float c = 0.f;
#pragma unroll
      for (int i = 0; i < 16; ++i) {
        const float qi = __shfl(q, ihalf + i);
        c += qi * (float)G[jit * 1024 + (ihalf + i) * 32 + tq];
      }
      c += __shfl_xor(c, 32);
      float mval = c;
#pragma unroll
      for (int m = 1; m < 32; m <<= 1) mval += __shfl_xor(mval, m);
      mval *= (1.f / 32.f);
      const float dl = c - mval;
      float var = dl * dl;
#pragma unroll
      for (int m = 1; m < 32; m <<= 1) var += __shfl_xor(var, m);
      var *= (1.f / 32.f);
      q = dl * rsqrtf(var + 1e-5f);
    }
    if (lane < 32) qs[lane] = q;
  }
  __syncthreads();

  for (int h = tid; h < H_DIM; h += 256) {
    const size_t xi = (size_t)row * H_DIM + h;
    float acc = (float)Xh1Hi[xi] + (float)Xh1Lo[xi] + blin[h];
    const float* wr = Wlin + (size_t)h * 32;
#pragma unroll
    for (int t2 = 0; t2 < 32; ++t2) acc += qs[t2] * wr[t2];
    out[xi] = acc;
  }
}

// ---------------------------------------------------------------------------
// Workspace (~233 MB): Whh_f 33.5 | Wih_f 33.5 | inp_f 16.8 | Gin2 67.1 |
// Xh 16.9 | XhHi 16.8 | XhLo 16.8 | Wq/Wr 2.1 | wbpad | Wall/RVall 4.2 |
// Gbuf f16 25.2
// ---------------------------------------------------------------------------
extern "C" void kernel_launch(void* const* d_in, const int* in_sizes, int n_in,
                              void* d_out, int out_size, void* d_ws, size_t ws_size,
                              hipStream_t stream)
{
  (void)in_sizes; (void)n_in; (void)out_size; (void)ws_size;
  const float* inp  = (const float*)d_in[0];
  const float* h0   = (const float*)d_in[1];
  const float* c0   = (const float*)d_in[2];
  const float* F0   = (const float*)d_in[3];
  const float* Wih  = (const float*)d_in[4];
  const float* Whh  = (const float*)d_in[5];
  const float* bih  = (const float*)d_in[6];
  const float* bhh  = (const float*)d_in[7];
  const float* Www  = (const float*)d_in[8];
  const float* Wwb  = (const float*)d_in[9];
  const float* Wrw  = (const float*)d_in[10];
  const float* Wrb  = (const float*)d_in[11];
  const float* Wlin = (const float*)d_in[12];
  const float* blin = (const float*)d_in[13];
  float* out = (float*)d_out;

  char* p = (char*)d_ws;
  auto alloc = [&](size_t bytes) {
    char* r = p;
    p += (bytes + 255) & ~(size_t)255;
    return r;
  };
  _Float16* Whh_f = (_Float16*)alloc(16777216ull * 2);   // 33.5 MB
  _Float16* Wih_f = (_Float16*)alloc(16777216ull * 2);   // 33.5 MB
  _Float16* inp_f = (_Float16*)alloc(8388608ull * 2);    // 16.8 MB
  _Float16* Gin2  = (_Float16*)alloc(33554432ull * 2);   // 67.1 MB fp16
  _Float16* Xh    = (_Float16*)alloc(257ull * 32768 * 2);// 16.9 MB
  bf16*     XhHi  = (bf16*)alloc(8388608ull * 2);        // 16.8 MB dedicated
  bf16*     XhLo  = (bf16*)alloc(8388608ull * 2);        // 16.8 MB dedicated
  bf16*  Wq_hi  = (bf16*)alloc(262144ull * 2);
  bf16*  Wq_lo  = (bf16*)alloc(262144ull * 2);
  bf16*  Wr_hi  = (bf16*)alloc(262144ull * 2);
  bf16*  Wr_lo  = (bf16*)alloc(262144ull * 2);
  float* wbpad  = (float*)alloc(128ull * 4);
  float* Wall   = (float*)alloc(524288ull * 4);          // 2.1 MB
  float* RVall  = (float*)alloc(524288ull * 4);          // 2.1 MB
  _Float16* Gbuf = (_Float16*)alloc(12582912ull * 2);    // 25.2 MB fp16

  prep_kernel<<<2048, 256, 0, stream>>>(Wih, Whh, inp, Www, Wwb, Wrw, h0,
                                        Wih_f, Whh_f, inp_f,
                                        Wq_hi, Wq_lo, Wr_hi, Wr_lo, wbpad,
                                        Xh, XhHi, XhLo, Wall, RVall);

  // Phase A: Gin2 = x @ W_ih^T + bias (fp16, coalesced transposed epilogue)
  gemm_f16<<<dim3(32, 64), 256, 0, stream>>>(inp_f, Wih_f, bih, bhh, Gin2,
                                             MROWS, G4, 2048);

  // Phase B+C+D1 fused: flag-free sentinel-dataflow LSTM + proj + F-scan
  {
    void* kargs[] = {
      (void*)&Whh_f, (void*)&Gin2, (void*)&bih, (void*)&bhh, (void*)&c0,
      (void*)&Wq_hi, (void*)&Wq_lo, (void*)&Wr_hi, (void*)&Wr_lo,
      (void*)&wbpad, (void*)&Wrb, (void*)&F0,
      (void*)&Xh, (void*)&XhHi, (void*)&XhLo,
      (void*)&Wall, (void*)&RVall, (void*)&Gbuf
    };
    hipLaunchCooperativeKernel((const void*)fused_rnn,
                               dim3(NWGL + NPRJ + NSCN), dim3(512),
                               kargs, 0, stream);
  }

  // Phase D2+E fused: q-readout + output
  qread_out<<<4096, 256, 0, stream>>>(Gbuf, RVall, XhHi, XhLo, Wlin, blin, out);
}

// Round 19
// 1866.439 us; speedup vs baseline: 1.0853x; 1.0853x over previous
//
#include <hip/hip_runtime.h>
#include <hip/hip_bf16.h>
#include <cstdint>
#include <cstddef>

// Problem constants: L=256, B=16, I=2048, H=2048, S=R=T=32
#define L_DIM 256
#define B_DIM 16
#define I_DIM 2048
#define H_DIM 2048
#define G4    8192
#define MROWS 4096
#define NWGL  128            // LSTM workgroups (each owns 16 hidden units)
#define NPRJ  16             // projection workgroups
#define NSCN  16             // scan workgroups (one per batch)

typedef __hip_bfloat16 bf16;
typedef __bf16 bf16x8_t __attribute__((ext_vector_type(8)));
typedef _Float16 f16x8_t __attribute__((ext_vector_type(8)));
typedef _Float16 f16x4_t __attribute__((ext_vector_type(4)));
typedef float f32x4_t   __attribute__((ext_vector_type(4)));

__device__ __forceinline__ bf16 f2b(float f) { return __float2bfloat16(f); }

__device__ __forceinline__ void gl_lds16(const void* g, void* l) {
  __builtin_amdgcn_global_load_lds(
      (const __attribute__((address_space(1))) unsigned int*)g,
      (__attribute__((address_space(3))) unsigned int*)l, 16, 0, 0);
}

__device__ __forceinline__ float sigmoidf_(float x) { return 1.f / (1.f + expf(-x)); }

// Coherent (IC-through) access helpers — proven fence-free protocol (r8).
__device__ __forceinline__ f16x8_t load_f16x8_sc(const _Float16* p) {
  f16x8_t r;
  asm volatile("global_load_dwordx4 %0, %1, off sc0 sc1" : "=v"(r) : "v"(p));
  return r;
}
__device__ __forceinline__ bf16x8_t load_bf16x8_sc(const bf16* p) {
  bf16x8_t r;
  asm volatile("global_load_dwordx4 %0, %1, off sc0 sc1" : "=v"(r) : "v"(p));
  return r;
}
__device__ __forceinline__ float load_f32_sc(const float* p) {
  float r;
  asm volatile("global_load_dword %0, %1, off sc0 sc1" : "=v"(r) : "v"(p));
  return r;
}
__device__ __forceinline__ void store_short_sc(void* p, unsigned int v) {
  asm volatile("global_store_short %0, %1, off sc0 sc1" :: "v"(p), "v"(v) : "memory");
}
__device__ __forceinline__ void store_f32_sc(void* p, float v) {
  asm volatile("global_store_dword %0, %1, off sc0 sc1" :: "v"(p), "v"(v) : "memory");
}

// ---------------------------------------------------------------------------
// K0: prep — fp16 casts, bf16 hi/lo FWM weights, h0 fp16
// ---------------------------------------------------------------------------
__global__ void prep_kernel(const float* __restrict__ Wih, const float* __restrict__ Whh,
                            const float* __restrict__ inp, const float* __restrict__ Www,
                            const float* __restrict__ Wwb, const float* __restrict__ Wrw,
                            const float* __restrict__ h0,
                            _Float16* __restrict__ Wih_f, _Float16* __restrict__ Whh_f,
                            _Float16* __restrict__ inp_f,
                            bf16* __restrict__ Wq_hi, bf16* __restrict__ Wq_lo,
                            bf16* __restrict__ Wr_hi, bf16* __restrict__ Wr_lo,
                            float* __restrict__ wbpad,
                            _Float16* __restrict__ Xh0)
{
  size_t idx0 = (size_t)blockIdx.x * blockDim.x + threadIdx.x;
  size_t stride = (size_t)gridDim.x * blockDim.x;
  for (size_t i = idx0; i < 16777216ull; i += stride) {
    Wih_f[i] = (_Float16)Wih[i];
    Whh_f[i] = (_Float16)Whh[i];
  }
  for (size_t i = idx0; i < 8388608ull; i += stride) inp_f[i] = (_Float16)inp[i];
  for (size_t i = idx0; i < 262144ull; i += stride) {
    size_t r = i >> 11;
    float q = (r < 97) ? Www[i] : 0.f;
    bf16 qh = f2b(q);
    Wq_hi[i] = qh;
    Wq_lo[i] = f2b(q - (float)qh);
    float rr = Wrw[i];
    bf16 rh = f2b(rr);
    Wr_hi[i] = rh;
    Wr_lo[i] = f2b(rr - (float)rh);
  }
  for (size_t i = idx0; i < 128ull; i += stride) wbpad[i] = (i < 97) ? Wwb[i] : 0.f;
  for (size_t i = idx0; i < 32768ull; i += stride) Xh0[i] = (_Float16)h0[i];
}

// ---------------------------------------------------------------------------
// K1: fp16 NT GEMM  C = A * B^T + bias -> fp16 Gin2[t][wg][gate][jj][bb].
// Coalesced f16x4 epilogue (round 16, proven).
// ---------------------------------------------------------------------------
__global__ __launch_bounds__(256) void gemm_f16(const _Float16* __restrict__ A,
                                                const _Float16* __restrict__ B,
                                                const float* __restrict__ bih,
                                                const float* __restrict__ bhh,
                                                _Float16* __restrict__ Gin2,
                                                int M, int N, int K)
{
  __shared__ __align__(16) _Float16 As[128 * 32];
  __shared__ __align__(16) _Float16 Bs[128 * 32];
  const int tid  = threadIdx.x;
  const int lane = tid & 63;
  const int w    = tid >> 6;
  const int wm   = w >> 1, wn = w & 1;
  const int m0   = blockIdx.x * 128, n0 = blockIdx.y * 128;

  f32x4_t acc[4][4];
#pragma unroll
  for (int m = 0; m < 4; ++m)
#pragma unroll
    for (int n = 0; n < 4; ++n) acc[m][n] = (f32x4_t){0.f, 0.f, 0.f, 0.f};

  for (int k0 = 0; k0 < K; k0 += 32) {
#pragma unroll
    for (int r = 0; r < 2; ++r) {
      const int base = w * 2048 + r * 1024;
      const int off  = base + lane * 16;
      const int e    = off >> 1;
      const int row  = e >> 5;
      const int col  = e & 31;
      gl_lds16(A + (size_t)(m0 + row) * K + (k0 + col), (char*)As + base);
      gl_lds16(B + (size_t)(n0 + row) * K + (k0 + col), (char*)Bs + base);
    }
    __syncthreads();

    f16x8_t af[4], bfr[4];
    const int kb = (lane >> 4) * 16;
#pragma unroll
    for (int m = 0; m < 4; ++m)
      af[m] = *reinterpret_cast<const f16x8_t*>((const char*)As + (wm * 64 + m * 16 + (lane & 15)) * 64 + kb);
#pragma unroll
    for (int n = 0; n < 4; ++n)
      bfr[n] = *reinterpret_cast<const f16x8_t*>((const char*)Bs + (wn * 64 + n * 16 + (lane & 15)) * 64 + kb);
#pragma unroll
    for (int m = 0; m < 4; ++m)
#pragma unroll
      for (int n = 0; n < 4; ++n)
        acc[m][n] = __builtin_amdgcn_mfma_f32_16x16x32_f16(af[m], bfr[n], acc[m][n], 0, 0, 0);
    __syncthreads();
  }

  const int jj = lane & 15;
#pragma unroll
  for (int n = 0; n < 4; ++n) {
    const int colb = n0 + wn * 64 + n * 16;
    const int gate = colb >> 11;
    const int wg   = (colb & 2047) >> 4;
    const float bv = bih[colb + jj] + bhh[colb + jj];
#pragma unroll
    for (int m = 0; m < 4; ++m) {
      const int rowb = m0 + wm * 64 + m * 16;
      const int t = rowb >> 4;
      f16x4_t v4;
#pragma unroll
      for (int r = 0; r < 4; ++r) v4[r] = (_Float16)(acc[m][n][r] + bv);
      *reinterpret_cast<f16x4_t*>(
          Gin2 + (((size_t)t * NWGL + wg) * 4 + gate) * 256 + jj * 16 + (lane >> 4) * 4) = v4;
    }
  }
}

// ---------------------------------------------------------------------------
// K2: FUSED persistent RNN (160 WGs x 512 thr, cooperative) — round 16
// structure (proven green); ROUND 19: LSTM Gin2 loads hoisted ABOVE the
// flag poll (Gin2 is precomputed, no dependence on the flag) so their
// latency hides under the wait.
// ---------------------------------------------------------------------------
__global__ __launch_bounds__(512, 2) void fused_rnn(
    const _Float16* __restrict__ Whh,
    const _Float16* __restrict__ Gin2,   // (256,128,4,16,16) fp16
    const float* __restrict__ bih, const float* __restrict__ bhh,
    const float* __restrict__ c0,
    const bf16* __restrict__ Wq_hi, const bf16* __restrict__ Wq_lo,
    const bf16* __restrict__ Wr_hi, const bf16* __restrict__ Wr_lo,
    const float* __restrict__ wbpad, const float* __restrict__ Wrb,
    const float* __restrict__ F0,
    _Float16* __restrict__ Xh,
    bf16* __restrict__ XhHi, bf16* __restrict__ XhLo,
    float* __restrict__ Wall, float* __restrict__ RVall,
    _Float16* __restrict__ Gbuf,
    int* lflags, int* pflags)
{
  __shared__ float part[8][4][16][17];          // lstm reduce; proj uses [][0]
  __shared__ float s_s[32], s_r[32], s_tv[32], s_bb;
  __shared__ float s_rv[128];
  __shared__ float s_v[32];
  __shared__ float s_red[8];

  const int wgid = blockIdx.x;
  const int tid  = threadIdx.x;
  const int lane = tid & 63;
  const int wv   = tid >> 6;          // 0..7

  if (wgid < NWGL) {
    // ===================== LSTM =====================
    const int wg = wgid;
    const int j0 = wg * 16;
    const int kw = wv * 256;

    f16x8_t whh[4][8];
    {
      const int nn  = lane & 15;
      const int kfo = (lane >> 4) * 8;
#pragma unroll
      for (int g = 0; g < 4; ++g) {
        const size_t grow = (size_t)(g * H_DIM + j0 + nn) * 2048;
#pragma unroll
        for (int ks = 0; ks < 8; ++ks)
          whh[g][ks] = *reinterpret_cast<const f16x8_t*>(Whh + grow + kw + ks * 32 + kfo);
      }
    }

    float c_reg = 0.f, cbr0 = 0.f, cbr1 = 0.f, cbr2 = 0.f, cbr3 = 0.f;
    if (tid < 256) {
      const int bb = tid & 15, jj = tid >> 4;
      const int j = j0 + jj;
      c_reg = c0[bb * H_DIM + j];
      cbr0 = bih[0 * H_DIM + j] + bhh[0 * H_DIM + j];
      cbr1 = bih[1 * H_DIM + j] + bhh[1 * H_DIM + j];
      cbr2 = bih[2 * H_DIM + j] + bhh[2 * H_DIM + j];
      cbr3 = bih[3 * H_DIM + j] + bhh[3 * H_DIM + j];
    }

    const size_t arow = (size_t)(lane & 15) * 2048 + kw + (lane >> 4) * 8;
    const int fidx = ((wv << 4) + (lane & 15)) << 4;   // this wave's producers

    for (int t = 0; t < L_DIM; ++t) {
      // Gin2 loads issued BEFORE the poll — latency hides under the wait
      float gin0 = 0.f, gin1 = 0.f, gin2v = 0.f, gin3 = 0.f;
      if (tid < 256) {
        const _Float16* gbase = Gin2 + ((size_t)t * NWGL + wg) * 1024;
        gin0  = (float)gbase[0 * 256 + tid];
        gin1  = (float)gbase[1 * 256 + tid];
        gin2v = (float)gbase[2 * 256 + tid];
        gin3  = (float)gbase[3 * 256 + tid];
      }

      if (t > 0) {
        while (true) {
          const int v = __hip_atomic_load(&lflags[fidx], __ATOMIC_RELAXED,
                                          __HIP_MEMORY_SCOPE_AGENT);
          if (__all(v >= t)) break;
          __builtin_amdgcn_s_sleep(1);
        }
      }

      const size_t hoff = (size_t)t * 32768 + arow;
      f16x8_t hf[8];
#pragma unroll
      for (int ks = 0; ks < 8; ++ks)
        hf[ks] = load_f16x8_sc(Xh + hoff + ks * 32);
      asm volatile("s_waitcnt vmcnt(0)" ::: "memory");
      __builtin_amdgcn_sched_barrier(0);   // rule #18

      f32x4_t acc[4];
#pragma unroll
      for (int g = 0; g < 4; ++g) acc[g] = (f32x4_t){0.f, 0.f, 0.f, 0.f};
#pragma unroll
      for (int ks = 0; ks < 8; ++ks) {
#pragma unroll
        for (int g = 0; g < 4; ++g)
          acc[g] = __builtin_amdgcn_mfma_f32_16x16x32_f16(hf[ks], whh[g][ks], acc[g], 0, 0, 0);
      }
#pragma unroll
      for (int g = 0; g < 4; ++g)
#pragma unroll
        for (int r = 0; r < 4; ++r)
          part[wv][g][(lane >> 4) * 4 + r][lane & 15] = acc[g][r];
      __syncthreads();

      if (tid < 256) {
        const int bb = tid & 15, jj = tid >> 4;
        float g4[4] = {gin0, gin1, gin2v, gin3};
        const float cb4[4] = {cbr0, cbr1, cbr2, cbr3};
#pragma unroll
        for (int g = 0; g < 4; ++g) {
          float s = 0.f;
#pragma unroll
          for (int v = 0; v < 8; ++v) s += part[v][g][bb][jj];
          g4[g] += s + cb4[g];
        }
        const float i_ = sigmoidf_(g4[0]);
        const float f_ = sigmoidf_(g4[1]);
        const float g_ = tanhf(g4[2]);
        const float o_ = sigmoidf_(g4[3]);
        c_reg = f_ * c_reg + i_ * g_;
        const float h = o_ * tanhf(c_reg);
        const int bj = bb * 2048 + j0 + jj;
        const _Float16 hF = (_Float16)h;
        const bf16 hhv = f2b(h);
        const bf16 hlv = f2b(h - (float)hhv);
        const size_t xi = ((size_t)t * 16 + bb) * 2048 + j0 + jj;
        store_short_sc(Xh + (size_t)(t + 1) * 32768 + bj,
                       (unsigned int)__builtin_bit_cast(unsigned short, hF));
        store_short_sc(XhHi + xi,
                       (unsigned int)__builtin_bit_cast(unsigned short, hhv));
        store_short_sc(XhLo + xi,
                       (unsigned int)__builtin_bit_cast(unsigned short, hlv));
      }
      asm volatile("s_waitcnt vmcnt(0)" ::: "memory");
      __syncthreads();

      if (tid == 0)
        __hip_atomic_store(&lflags[wg << 4], t + 1, __ATOMIC_RELAXED,
                           __HIP_MEMORY_SCOPE_AGENT);
    }

  } else if (wgid < NWGL + NPRJ) {
    // ===================== PROJECTION =====================
    const int p   = wgid - NWGL;
    const int kw  = wv * 256;
    const int nn  = lane & 15;
    const int kfo = (lane >> 4) * 8;

    bf16x8_t wbh[8], wbl[8];
    {
      const bf16* Bh = (p < 8) ? Wq_hi : Wr_hi;
      const bf16* Bl = (p < 8) ? Wq_lo : Wr_lo;
      const int brow = (p < 8) ? (p * 16 + nn) : ((p - 8) * 16 + nn);
#pragma unroll
      for (int ks = 0; ks < 8; ++ks) {
        const size_t o = (size_t)brow * 2048 + kw + ks * 32 + kfo;
        wbh[ks] = *reinterpret_cast<const bf16x8_t*>(Bh + o);
        wbl[ks] = *reinterpret_cast<const bf16x8_t*>(Bl + o);
      }
    }
    float biasv = 0.f;
    if (tid < 256) {
      const int oo = tid >> 4;
      biasv = (p < 8) ? wbpad[p * 16 + oo] : Wrb[(p - 8) * 16 + oo];
    }

    const size_t axrow = (size_t)(lane & 15) * 2048 + kw + kfo;

    for (int t = 0; t < L_DIM; ++t) {
      while (true) {
        const int v0 = __hip_atomic_load(&lflags[lane << 4], __ATOMIC_RELAXED,
                                         __HIP_MEMORY_SCOPE_AGENT);
        const int v1 = __hip_atomic_load(&lflags[(64 + lane) << 4], __ATOMIC_RELAXED,
                                         __HIP_MEMORY_SCOPE_AGENT);
        if (__all(v0 > t && v1 > t)) break;
        __builtin_amdgcn_s_sleep(1);
      }

      const size_t xoff = (size_t)t * 32768 + axrow;
      bf16x8_t xh[8], xl[8];
#pragma unroll
      for (int ks = 0; ks < 8; ++ks) {
        xh[ks] = load_bf16x8_sc(XhHi + xoff + ks * 32);
        xl[ks] = load_bf16x8_sc(XhLo + xoff + ks * 32);
      }
      asm volatile("s_waitcnt vmcnt(0)" ::: "memory");
      __builtin_amdgcn_sched_barrier(0);

      f32x4_t acc = {0.f, 0.f, 0.f, 0.f};
#pragma unroll
      for (int ks = 0; ks < 8; ++ks) {
        acc = __builtin_amdgcn_mfma_f32_16x16x32_bf16(xh[ks], wbh[ks], acc, 0, 0, 0);
        acc = __builtin_amdgcn_mfma_f32_16x16x32_bf16(xh[ks], wbl[ks], acc, 0, 0, 0);
        acc = __builtin_amdgcn_mfma_f32_16x16x32_bf16(xl[ks], wbh[ks], acc, 0, 0, 0);
      }
#pragma unroll
      for (int r = 0; r < 4; ++r)
        part[wv][0][(lane >> 4) * 4 + r][lane & 15] = acc[r];
      __syncthreads();

      if (tid < 256) {
        const int bb = tid & 15, oo = tid >> 4;
        float s = 0.f;
#pragma unroll
        for (int v = 0; v < 8; ++v) s += part[v][0][bb][oo];
        s += biasv;
        float* dst;
        if (p < 8) {
          dst = Wall + (size_t)(t * 16 + bb) * 128 + p * 16 + oo;
        } else {
          s = tanhf(s);
          dst = RVall + (size_t)(t * 16 + bb) * 128 + (p - 8) * 16 + oo;
        }
        store_f32_sc(dst, s);
      }
      asm volatile("s_waitcnt vmcnt(0)" ::: "memory");
      __syncthreads();

      if (tid == 0)
        __hip_atomic_store(&pflags[p << 4], t + 1, __ATOMIC_RELAXED,
                           __HIP_MEMORY_SCOPE_AGENT);
    }

  } else {
    // ===================== FWM F-SCAN =====================
    const int b     = wgid - NWGL - NPRJ;
    const int si    = lane >> 1;
    const int rbase = 16 * (lane & 1);
    const int tl    = lane & 31;

    float F[16][4];
#pragma unroll
    for (int i = 0; i < 16; ++i)
#pragma unroll
      for (int j = 0; j < 4; ++j)
        F[i][j] = F0[((size_t)b * 1024 + (16 * lane + i)) * 32 + 4 * wv + j];

    float N = 0.f;
    {
      float loc = 0.f;
#pragma unroll
      for (int i = 0; i < 16; ++i)
#pragma unroll
        for (int j = 0; j < 4; ++j) loc += F[i][j] * F[i][j];
#pragma unroll
      for (int m = 1; m < 64; m <<= 1) loc += __shfl_xor(loc, m);
      if (lane == 0) s_red[wv] = loc;
      __syncthreads();
#pragma unroll
      for (int k = 0; k < 8; ++k) N += s_red[k];
    }

    for (int t = 0; t < 256; ++t) {
      while (true) {
        const int v = __hip_atomic_load(&pflags[(lane & 15) << 4], __ATOMIC_RELAXED,
                                        __HIP_MEMORY_SCOPE_AGENT);
        if (__all(v > t)) break;
        __builtin_amdgcn_s_sleep(1);
      }

      float wpre = 0.f, rvpre = 0.f;
      if (tid < 97)  wpre = load_f32_sc(Wall + (size_t)(t * 16 + b) * 128 + tid);
      if (tid >= 128 && tid < 256)
        rvpre = load_f32_sc(RVall + (size_t)(t * 16 + b) * 128 + tid - 128);
      asm volatile("s_waitcnt vmcnt(0)" ::: "memory");
      __syncthreads();                // A
      if (tid < 32)       s_s[tid]       = tanhf(wpre);
      else if (tid < 64)  s_r[tid - 32]  = tanhf(wpre);
      else if (tid < 96)  s_tv[tid - 64] = tanhf(wpre);
      else if (tid == 96) s_bb           = sigmoidf_(wpre + 1.f);
      else if (tid >= 128 && tid < 256) s_rv[tid - 128] = rvpre;
      __syncthreads();                // B

      const float sv = s_s[si];
      float sr[16];
#pragma unroll
      for (int i = 0; i < 16; ++i) sr[i] = sv * s_r[rbase + i];

      float vv4[4];
#pragma unroll
      for (int j = 0; j < 4; ++j) {
        float pp = 0.f;
#pragma unroll
        for (int i = 0; i < 16; ++i) pp += sr[i] * F[i][j];
#pragma unroll
        for (int m = 1; m < 64; m <<= 1) pp += __shfl_xor(pp, m);
        vv4[j] = pp;
      }
      if (lane == 0) {
#pragma unroll
        for (int j = 0; j < 4; ++j) s_v[4 * wv + j] = vv4[j];
      }
      __syncthreads();                // C

      const float vt  = s_v[tl];
      const float ut  = s_bb * (s_tv[tl] - vt);
      const float sl  = s_s[tl];
      const float rl  = s_r[tl];
      float uv = ut * vt, uu = ut * ut, ss = sl * sl, rr = rl * rl;
#pragma unroll
      for (int m = 1; m < 32; m <<= 1) {
        uv += __shfl_xor(uv, m);
        uu += __shfl_xor(uu, m);
        ss += __shfl_xor(ss, m);
        rr += __shfl_xor(rr, m);
      }
      const float Np  = N + 2.f * uv + ss * rr * uu;
      const float n_  = sqrtf(Np);
      const float inv = 1.f / (fmaxf(n_ - 1.f, 0.f) + 1.f);
      N = Np * inv * inv;

      float uw[4];
#pragma unroll
      for (int j = 0; j < 4; ++j) uw[j] = __shfl(ut, 4 * wv + j);
#pragma unroll
      for (int i = 0; i < 16; ++i)
#pragma unroll
        for (int j = 0; j < 4; ++j)
          F[i][j] = (F[i][j] + sr[i] * uw[j]) * inv;

      _Float16* gout = Gbuf + ((size_t)(t * 16 + b) * 3) * 1024;
#pragma unroll
      for (int jit = 0; jit < 3; ++jit) {
        float rjv[16];
#pragma unroll
        for (int i = 0; i < 16; ++i) rjv[i] = s_rv[32 + 32 * jit + rbase + i];
        f16x4_t gv;
#pragma unroll
        for (int j = 0; j < 4; ++j) {
          float g = 0.f;
#pragma unroll
          for (int i = 0; i < 16; ++i) g += rjv[i] * F[i][j];
          g += __shfl_xor(g, 1);
          gv[j] = (_Float16)g;
        }
        if ((lane & 1) == 0)
          *reinterpret_cast<f16x4_t*>(gout + jit * 1024 + (lane >> 1) * 32 + 4 * wv) = gv;
      }
    }
  }
}

// ---------------------------------------------------------------------------
// K3: fused q-readout + output. One block per row (t*16+b).
// ---------------------------------------------------------------------------
__global__ __launch_bounds__(256) void qread_out(const _Float16* __restrict__ Gbuf,  // (4096,3,32,32) f16
                                                 const float* __restrict__ RVall,    // (4096,128)
                                                 const bf16* __restrict__ Xh1Hi,
                                                 const bf16* __restrict__ Xh1Lo,
                                                 const float* __restrict__ Wlin,     // (2048,32)
                                                 const float* __restrict__ blin,
                                                 float* __restrict__ out)
{
  __shared__ float qs[32];
  const int row = blockIdx.x;          // t*16+b
  const int tid = threadIdx.x;

  if (tid < 64) {
    const int lane  = tid;
    const int tq    = lane & 31;
    const int ihalf = (lane >> 5) * 16;
    const _Float16* G = Gbuf + (size_t)row * 3 * 1024;
    float q = RVall[(size_t)row * 128 + tq];
#pragma unroll 1
    for (int jit = 0; jit < 3; ++jit) {
      float c = 0.f;
#pragma unroll
      for (int i = 0; i < 16; ++i) {
        const float qi = __shfl(q, ihalf + i);
        c += qi * (float)G[jit * 1024 + (ihalf + i) * 32 + tq];
      }
      c += __shfl_xor(c, 32);
      float mval = c;
#pragma unroll
      for (int m = 1; m < 32; m <<= 1) mval += __shfl_xor(mval, m);
      mval *= (1.f / 32.f);
      const float dl = c - mval;
      float var = dl * dl;
#pragma unroll
      for (int m = 1; m < 32; m <<= 1) var += __shfl_xor(var, m);
      var *= (1.f / 32.f);
      q = dl * rsqrtf(var + 1e-5f);
    }
    if (lane < 32) qs[lane] = q;
  }
  __syncthreads();

  for (int h = tid; h < H_DIM; h += 256) {
    const size_t xi = (size_t)row * H_DIM + h;
    float acc = (float)Xh1Hi[xi] + (float)Xh1Lo[xi] + blin[h];
    const float* wr = Wlin + (size_t)h * 32;
#pragma unroll
    for (int t2 = 0; t2 < 32; ++t2) acc += qs[t2] * wr[t2];
    out[xi] = acc;
  }
}

// ---------------------------------------------------------------------------
// Workspace (~216 MB): Whh_f 33.5 | Wih_f 33.5 | inp_f 16.8 (XhHi alias —
// safe: gemm_f16 fully consumes inp_f before fused launches) | Gin2 fp16
// 67.1 | Xh 16.9 | XhLo 16.8 | Wq/Wr 2.1 | Wall/RVall 4.2 | Gbuf fp16 25.2 |
// flags 10KB
// ---------------------------------------------------------------------------
extern "C" void kernel_launch(void* const* d_in, const int* in_sizes, int n_in,
                              void* d_out, int out_size, void* d_ws, size_t ws_size,
                              hipStream_t stream)
{
  (void)in_sizes; (void)n_in; (void)out_size; (void)ws_size;
  const float* inp  = (const float*)d_in[0];
  const float* h0   = (const float*)d_in[1];
  const float* c0   = (const float*)d_in[2];
  const float* F0   = (const float*)d_in[3];
  const float* Wih  = (const float*)d_in[4];
  const float* Whh  = (const float*)d_in[5];
  const float* bih  = (const float*)d_in[6];
  const float* bhh  = (const float*)d_in[7];
  const float* Www  = (const float*)d_in[8];
  const float* Wwb  = (const float*)d_in[9];
  const float* Wrw  = (const float*)d_in[10];
  const float* Wrb  = (const float*)d_in[11];
  const float* Wlin = (const float*)d_in[12];
  const float* blin = (const float*)d_in[13];
  float* out = (float*)d_out;

  char* p = (char*)d_ws;
  auto alloc = [&](size_t bytes) {
    char* r = p;
    p += (bytes + 255) & ~(size_t)255;
    return r;
  };
  _Float16* Whh_f = (_Float16*)alloc(16777216ull * 2);   // 33.5 MB
  _Float16* Wih_f = (_Float16*)alloc(16777216ull * 2);   // 33.5 MB
  _Float16* inp_f = (_Float16*)alloc(8388608ull * 2);    // 16.8 MB
  _Float16* Gin2  = (_Float16*)alloc(33554432ull * 2);   // 67.1 MB fp16
  _Float16* Xh    = (_Float16*)alloc(257ull * 32768 * 2);// 16.9 MB
  bf16*     XhLo  = (bf16*)alloc(8388608ull * 2);        // 16.8 MB dedicated
  bf16*  Wq_hi  = (bf16*)alloc(262144ull * 2);
  bf16*  Wq_lo  = (bf16*)alloc(262144ull * 2);
  bf16*  Wr_hi  = (bf16*)alloc(262144ull * 2);
  bf16*  Wr_lo  = (bf16*)alloc(262144ull * 2);
  float* wbpad  = (float*)alloc(128ull * 4);
  float* Wall   = (float*)alloc(524288ull * 4);          // 2.1 MB
  float* RVall  = (float*)alloc(524288ull * 4);          // 2.1 MB
  _Float16* Gbuf = (_Float16*)alloc(12582912ull * 2);    // 25.2 MB fp16
  int*   flags  = (int*)alloc((NWGL + NPRJ) * 64);       // lflags + pflags
  int*   lflags = flags;
  int*   pflags = flags + NWGL * 16;
  // alias (safe: gemm_f16 consumes all of inp_f before fused_rnn launches):
  bf16*  XhHi  = (bf16*)inp_f;

  prep_kernel<<<2048, 256, 0, stream>>>(Wih, Whh, inp, Www, Wwb, Wrw, h0,
                                        Wih_f, Whh_f, inp_f,
                                        Wq_hi, Wq_lo, Wr_hi, Wr_lo, wbpad, Xh);

  // Phase A: Gin2 = x @ W_ih^T + bias (fp16, coalesced transposed epilogue)
  gemm_f16<<<dim3(32, 64), 256, 0, stream>>>(inp_f, Wih_f, bih, bhh, Gin2,
                                             MROWS, G4, 2048);

  // Phase B+C+D1 fused: cooperative pipelined LSTM + proj + F-scan
  hipMemsetAsync(flags, 0, (NWGL + NPRJ) * 64, stream);
  {
    void* kargs[] = {
      (void*)&Whh_f, (void*)&Gin2, (void*)&bih, (void*)&bhh, (void*)&c0,
      (void*)&Wq_hi, (void*)&Wq_lo, (void*)&Wr_hi, (void*)&Wr_lo,
      (void*)&wbpad, (void*)&Wrb, (void*)&F0,
      (void*)&Xh, (void*)&XhHi, (void*)&XhLo,
      (void*)&Wall, (void*)&RVall, (void*)&Gbuf,
      (void*)&lflags, (void*)&pflags
    };
    hipLaunchCooperativeKernel((const void*)fused_rnn,
                               dim3(NWGL + NPRJ + NSCN), dim3(512),
                               kargs, 0, stream);
  }

  // Phase D2+E fused: q-readout + output
  qread_out<<<4096, 256, 0, stream>>>(Gbuf, RVall, XhHi, XhLo, Wlin, blin, out);
}